// Round 1
// 369.734 us; speedup vs baseline: 1.0375x; 1.0375x over previous
//
#include <hip/hip_runtime.h>

#define NBATCH 4
#define NN 2048
#define NR 8192            // NBATCH*NN rows
#define TOPK 10

typedef __attribute__((ext_vector_type(4))) float f32x4;
typedef __attribute__((ext_vector_type(8))) short bf16x8;

__device__ inline unsigned short f2bf(float x) {
    unsigned u = __float_as_uint(x);
    unsigned r = (u + 0x7FFF + ((u >> 16) & 1)) >> 16;
    return (unsigned short)r;
}

// ---------------- K1: encoders + fusion + q/k projection (bf16, K=32 padded)
__global__ __launch_bounds__(256) void k1_encode(
    const float* __restrict__ xd, const float* __restrict__ xs,
    const float* __restrict__ Wd, const float* __restrict__ bd,
    const float* __restrict__ Ws, const float* __restrict__ bs,
    const float* __restrict__ Wf, const float* __restrict__ bf,
    const float* __restrict__ Wq, const float* __restrict__ Wk,
    unsigned short* __restrict__ qh, unsigned short* __restrict__ kh)
{
    int wave = threadIdx.x >> 6;
    int lane = threadIdx.x & 63;
    int r = blockIdx.x * 4 + wave;        // 0..8191

    __shared__ float xm[4][16];
    __shared__ float xst[4][8];
    __shared__ float hc[4][128];
    __shared__ float hh[4][64];

    const float* xdr = xd + (size_t)r * 512;
    float acc = 0.f;
    #pragma unroll
    for (int j = 0; j < 8; ++j) acc += xdr[lane + 64*j];
    acc += __shfl_xor(acc, 16);
    acc += __shfl_xor(acc, 32);
    if (lane < 16) xm[wave][lane] = acc * (1.0f/32.0f);
    if (lane < 8)  xst[wave][lane] = xs[(size_t)r*8 + lane];
    __syncthreads();

    float a1 = bd[lane];
    #pragma unroll
    for (int d = 0; d < 16; ++d) a1 += xm[wave][d] * Wd[d*64 + lane];
    a1 = fmaxf(a1, 0.f);
    float a2 = bs[lane];
    #pragma unroll
    for (int d = 0; d < 8; ++d) a2 += xst[wave][d] * Ws[d*64 + lane];
    a2 = fmaxf(a2, 0.f);
    hc[wave][lane] = a1;
    hc[wave][64 + lane] = a2;
    __syncthreads();

    // 4 accumulators: break the 128-long fma dependency chain
    float hv0 = bf[lane], hv1 = 0.f, hv2 = 0.f, hv3 = 0.f;
    #pragma unroll
    for (int j = 0; j < 128; j += 4) {
        hv0 += hc[wave][j]   * Wf[(j)*64   + lane];
        hv1 += hc[wave][j+1] * Wf[(j+1)*64 + lane];
        hv2 += hc[wave][j+2] * Wf[(j+2)*64 + lane];
        hv3 += hc[wave][j+3] * Wf[(j+3)*64 + lane];
    }
    hh[wave][lane] = (hv0 + hv1) + (hv2 + hv3);
    __syncthreads();

    float qv0 = 0.f, qv1 = 0.f, kv0 = 0.f, kv1 = 0.f;
    #pragma unroll
    for (int j = 0; j < 64; j += 2) {
        float h0 = hh[wave][j], h1 = hh[wave][j+1];
        qv0 += h0 * Wq[(j)*64   + lane];
        qv1 += h1 * Wq[(j+1)*64 + lane];
        kv0 += h0 * Wk[(j)*64   + lane];
        kv1 += h1 * Wk[(j+1)*64 + lane];
    }
    float qv = qv0 + qv1, kv = kv0 + kv1;
    // lane = head*16 + dim; layout qh[(b*4+h)*2048 + n][32], dims 16..31 = 0
    int b = r >> 11, n = r & 2047;
    int head = lane >> 4, dim = lane & 15;
    size_t base = ((size_t)(b*4 + head) * NN + n) * 32;
    qh[base + dim] = f2bf(qv);
    qh[base + 16 + dim] = 0;
    kh[base + dim] = f2bf(kv);
    kh[base + 16 + dim] = 0;
}

// ---------------- K2A: per-(b,h,row) softmax stats via MFMA (2 sweeps) ------
__global__ __launch_bounds__(256) void k2A_stats(
    const unsigned short* __restrict__ qh, const unsigned short* __restrict__ kh,
    float* __restrict__ Mf, float* __restrict__ Rf)
{
    const float C1 = 0.36067376022224085f;   // 0.25 * log2(e)
    int bh = blockIdx.x >> 7;                // 16 (b,h) pairs
    int rg = blockIdx.x & 127;               // row group of 16
    int w = threadIdx.x >> 6, l = threadIdx.x & 63;
    int quad = l >> 4, lo = l & 15;

    bf16x8 afrag = *(const bf16x8*)(qh + ((size_t)bh * NN + rg*16 + lo) * 32 + quad*8);
    const unsigned short* kbase = kh + (size_t)bh * NN * 32;

    __shared__ float redA[4][16];
    __shared__ float Mrow[16];

    float Mloc[4] = {-3e38f,-3e38f,-3e38f,-3e38f};
    for (int t = 0; t < 32; ++t) {
        int m0 = w*512 + t*16;
        bf16x8 bfrag = *(const bf16x8*)(kbase + (size_t)(m0 + lo) * 32 + quad*8);
        f32x4 acc = {0.f,0.f,0.f,0.f};
        acc = __builtin_amdgcn_mfma_f32_16x16x32_bf16(afrag, bfrag, acc, 0, 0, 0);
        #pragma unroll
        for (int rr = 0; rr < 4; ++rr) Mloc[rr] = fmaxf(Mloc[rr], acc[rr]);
    }
    #pragma unroll
    for (int d = 1; d <= 8; d <<= 1) {
        #pragma unroll
        for (int rr = 0; rr < 4; ++rr) Mloc[rr] = fmaxf(Mloc[rr], __shfl_xor(Mloc[rr], d));
    }
    if (lo == 0) {
        #pragma unroll
        for (int rr = 0; rr < 4; ++rr) redA[w][quad*4 + rr] = Mloc[rr];
    }
    __syncthreads();
    if (threadIdx.x < 16)
        Mrow[threadIdx.x] = fmaxf(fmaxf(redA[0][threadIdx.x], redA[1][threadIdx.x]),
                                  fmaxf(redA[2][threadIdx.x], redA[3][threadIdx.x]));
    __syncthreads();

    float mrr[4];
    #pragma unroll
    for (int rr = 0; rr < 4; ++rr) mrr[rr] = Mrow[quad*4 + rr];

    float Sloc[4] = {0.f,0.f,0.f,0.f};
    for (int t = 0; t < 32; ++t) {
        int m0 = w*512 + t*16;
        bf16x8 bfrag = *(const bf16x8*)(kbase + (size_t)(m0 + lo) * 32 + quad*8);
        f32x4 acc = {0.f,0.f,0.f,0.f};
        acc = __builtin_amdgcn_mfma_f32_16x16x32_bf16(afrag, bfrag, acc, 0, 0, 0);
        #pragma unroll
        for (int rr = 0; rr < 4; ++rr)
            Sloc[rr] += exp2f((acc[rr] - mrr[rr]) * C1);
    }
    #pragma unroll
    for (int d = 1; d <= 8; d <<= 1) {
        #pragma unroll
        for (int rr = 0; rr < 4; ++rr) Sloc[rr] += __shfl_xor(Sloc[rr], d);
    }
    if (lo == 0) {
        #pragma unroll
        for (int rr = 0; rr < 4; ++rr) redA[w][quad*4 + rr] = Sloc[rr];
    }
    __syncthreads();
    if (threadIdx.x < 16) {
        float S = redA[0][threadIdx.x] + redA[1][threadIdx.x]
                + redA[2][threadIdx.x] + redA[3][threadIdx.x];
        int row = rg*16 + threadIdx.x;
        Mf[(size_t)bh * NN + row] = 0.25f * Mrow[threadIdx.x];
        Rf[(size_t)bh * NN + row] = 1.0f / S;
    }
}

// ---------------- K2C: head-averaged values via MFMA + exact top-10 ---------
// top-k keys packed in u32: (bf16_value << 16) | (2047 - col). Lossless w.r.t.
// the previous u64 scheme because values are bf16-rounded (low 16 f32 bits 0).
__global__ __launch_bounds__(256) void k2C_topk(
    const unsigned short* __restrict__ qh, const unsigned short* __restrict__ kh,
    const float* __restrict__ Mf, const float* __restrict__ Rf,
    float* __restrict__ fV, int* __restrict__ fI)
{
    const float C1 = 0.36067376022224085f;   // 0.25 * log2(e)
    const float L2E = 1.4426950408889634f;
    int b  = blockIdx.x >> 7;
    int rg = blockIdx.x & 127;
    int w = threadIdx.x >> 6, l = threadIdx.x & 63;
    int quad = l >> 4, lo = l & 15;

    __shared__ unsigned short vt[16][2048];  // bf16 values, XOR-swizzled cols

    bf16x8 afrag[4];
    float b2[4][4], r4[4][4];
    #pragma unroll
    for (int h = 0; h < 4; ++h) {
        int bh = b*4 + h;
        afrag[h] = *(const bf16x8*)(qh + ((size_t)bh * NN + rg*16 + lo) * 32 + quad*8);
        #pragma unroll
        for (int rr = 0; rr < 4; ++rr) {
            int row = rg*16 + quad*4 + rr;
            b2[h][rr] = Mf[(size_t)bh * NN + row] * L2E;
            r4[h][rr] = Rf[(size_t)bh * NN + row] * 0.25f;
        }
    }

    int swz_w = quad << 4;                   // write swizzle = (row>>2)*16
    for (int t = 0; t < 32; ++t) {
        int m0 = w*512 + t*16;
        float vacc[4] = {0.f,0.f,0.f,0.f};
        #pragma unroll
        for (int h = 0; h < 4; ++h) {
            bf16x8 bfrag = *(const bf16x8*)(kh + ((size_t)(b*4+h) * NN + m0 + lo) * 32 + quad*8);
            f32x4 acc = {0.f,0.f,0.f,0.f};
            acc = __builtin_amdgcn_mfma_f32_16x16x32_bf16(afrag[h], bfrag, acc, 0, 0, 0);
            #pragma unroll
            for (int rr = 0; rr < 4; ++rr) {
                float e = exp2f(fmaf(acc[rr], C1, -b2[h][rr]));
                vacc[rr] = fmaf(e, r4[h][rr], vacc[rr]);
            }
        }
        #pragma unroll
        for (int rr = 0; rr < 4; ++rr)
            vt[quad*4 + rr][(m0 + lo) ^ swz_w] = f2bf(vacc[rr]);
    }
    __syncthreads();

    // top-10 per row; wave w handles rows 4w..4w+3
    for (int rr = 0; rr < 4; ++rr) {
        int row = w*4 + rr;
        int swz = (row >> 2) << 4;
        unsigned tk[TOPK];
        #pragma unroll
        for (int s = 0; s < TOPK; ++s) tk[s] = 0u;
        for (int j = 0; j < 16; ++j) {
            int m1 = 2*l + 128*j;
            unsigned pair = *(const unsigned*)&vt[row][m1 ^ swz];
            unsigned key0 = (pair << 16)          | (unsigned)(2047 - m1);
            unsigned key1 = (pair & 0xFFFF0000u)  | (unsigned)(2046 - m1);
            if (key0 > tk[TOPK-1]) {
                unsigned ck = key0;
                #pragma unroll
                for (int s = 0; s < TOPK; ++s) {
                    bool ins = ck > tk[s];
                    unsigned o = tk[s];
                    tk[s] = ins ? ck : o;
                    ck    = ins ? o  : ck;
                }
            }
            if (key1 > tk[TOPK-1]) {
                unsigned ck = key1;
                #pragma unroll
                for (int s = 0; s < TOPK; ++s) {
                    bool ins = ck > tk[s];
                    unsigned o = tk[s];
                    tk[s] = ins ? ck : o;
                    ck    = ins ? o  : ck;
                }
            }
        }
        // 10 rounds of 64-lane argmax on packed u32 keys (unique: idx in key)
        int rowg = b * NN + rg*16 + row;
        #pragma unroll 1
        for (int s = 0; s < TOPK; ++s) {
            unsigned kmax = tk[0];
            #pragma unroll
            for (int d = 1; d < 64; d <<= 1) {
                unsigned o = __shfl_xor(kmax, d);
                kmax = (o > kmax) ? o : kmax;
            }
            if (tk[0] == kmax) {   // exactly one winner pops its head
                #pragma unroll
                for (int q = 0; q < TOPK-1; ++q) tk[q] = tk[q+1];
                tk[TOPK-1] = 0u;
            }
            if (l == 0) {
                fV[(size_t)s * NR + rowg] = __uint_as_float(kmax & 0xFFFF0000u);
                fI[(size_t)s * NR + rowg] = 2047 - (int)(kmax & 0x7FFu);
            }
        }
    }
}

// ---------------- K3: A base = 0.3*prior; L = -A; fold 0.3*rowsum into diag -
__global__ __launch_bounds__(256) void k3_base(
    const float* __restrict__ prior, float* __restrict__ Lout,
    float* __restrict__ Aout)
{
    int r = blockIdx.x;
    const float4* pr = (const float4*)(prior + (size_t)r * NN);
    float4* Ar = (float4*)(Aout + (size_t)r * NN);
    float4* Lr = (float4*)(Lout + (size_t)r * NN);
    float sum = 0.f;
    for (int i = threadIdx.x; i < NN/4; i += 256) {
        float4 p = pr[i];
        float4 a; a.x = 0.3f*p.x; a.y = 0.3f*p.y; a.z = 0.3f*p.z; a.w = 0.3f*p.w;
        Ar[i] = a;
        float4 lv; lv.x = -a.x; lv.y = -a.y; lv.z = -a.z; lv.w = -a.w;
        Lr[i] = lv;
        sum += a.x + a.y + a.z + a.w;
    }
    #pragma unroll
    for (int o = 32; o > 0; o >>= 1) sum += __shfl_down(sum, o);
    __shared__ float wsum[4];
    if ((threadIdx.x & 63) == 0) wsum[threadIdx.x >> 6] = sum;
    __syncthreads();
    if (threadIdx.x == 0) {
        float tot = wsum[0] + wsum[1] + wsum[2] + wsum[3];
        // prior-part of degree straight onto the diagonal (stores above are
        // drained by the vmcnt(0) the compiler emits at __syncthreads)
        atomicAdd(&Lout[(size_t)r * NN + (r & 2047)], tot);
    }
}

// ---------------- K4: scatter symmetric sparse top-k; degree -> L diagonal --
// one thread per (s, r): 81920 threads, coalesced fV/fI loads (lanes share s)
__global__ __launch_bounds__(256) void k4_scatter(
    const float* __restrict__ fV, const int* __restrict__ fI,
    float* __restrict__ Lout, float* __restrict__ Aout)
{
    int wk = blockIdx.x * 256 + threadIdx.x;   // 0..81919
    int s = wk >> 13;                           // 0..9
    int r = wk & 8191;                          // 0..8191
    int b = r >> 11;
    int n = r & 2047;
    float wv = 0.35f * fV[(size_t)s * NR + r];  // 0.7 * 0.5 * val
    int j = fI[(size_t)s * NR + r];
    size_t ij = (size_t)r * NN + j;
    size_t ji = ((size_t)(b * NN + j)) * NN + n;
    atomicAdd(&Aout[ij],  wv);
    atomicAdd(&Aout[ji],  wv);
    atomicAdd(&Lout[ij], -wv);
    atomicAdd(&Lout[ji], -wv);
    atomicAdd(&Lout[((size_t)(b * NN + j)) * NN + j], wv);  // deg[j] -> diag j
    atomicAdd(&Lout[(size_t)r * NN + n],              wv);  // deg[r] -> diag r
}

extern "C" void kernel_launch(void* const* d_in, const int* in_sizes, int n_in,
                              void* d_out, int out_size, void* d_ws, size_t ws_size,
                              hipStream_t stream)
{
    const float* xd    = (const float*)d_in[0];
    const float* xs    = (const float*)d_in[1];
    const float* prior = (const float*)d_in[2];
    const float* Wd    = (const float*)d_in[3];
    const float* bd    = (const float*)d_in[4];
    const float* Ws    = (const float*)d_in[5];
    const float* bs    = (const float*)d_in[6];
    const float* Wf    = (const float*)d_in[7];
    const float* bf    = (const float*)d_in[8];
    const float* Wq    = (const float*)d_in[9];
    const float* Wk    = (const float*)d_in[10];

    float* Lout = (float*)d_out;
    float* Aout = Lout + (size_t)NR * NN;

    unsigned short* qh = (unsigned short*)d_ws;          // 16*2048*32 bf16 = 2MB
    unsigned short* kh = qh + (size_t)16 * NN * 32;      // 2MB
    float* Mf  = (float*)(kh + (size_t)16 * NN * 32);    // 16*2048
    float* Rf  = Mf + (size_t)16 * NN;
    float* fV  = Rf + (size_t)16 * NN;                   // 10*8192
    int*   fI  = (int*)(fV + (size_t)TOPK * NR);

    k1_encode<<<NR/4, 256, 0, stream>>>(xd, xs, Wd, bd, Ws, bs, Wf, bf, Wq, Wk, qh, kh);
    k2A_stats<<<16*128, 256, 0, stream>>>(qh, kh, Mf, Rf);
    k2C_topk<<<4*128, 256, 0, stream>>>(qh, kh, Mf, Rf, fV, fI);
    k3_base<<<NR, 256, 0, stream>>>(prior, Lout, Aout);
    k4_scatter<<<TOPK*NR/256, 256, 0, stream>>>(fV, fI, Lout, Aout);
}